// Round 6
// baseline (314.533 us; speedup 1.0000x reference)
//
#include <hip/hip_runtime.h>

// GCN1 on MI355X. Round-4 evidence: the random-gather consumers are stuck at
// ~93us INVARIANT to occupancy (245 vs 1960 blocks) and ILP (1x vs 4x), with
// every pipe idle -> hypothesis: TLB/page-walk serialization on random gathers
// over a 1024-page table. Round-5/6: counting-sort key extended to
// (dst_bucket, src>>16) = 1960 bins so gathers have page locality (64-128 page
// working set per run). Atomic-free scatter placement via per-block bin
// histograms + column scan. Round-6 fixes the compile error only:
// __builtin_nontemporal_load needs a clang ext_vector_type, not HIP's uint4.
//
// Algebra (validated r1-r4, absmax 3.9e-3): layer1 collapses to a scalar
// aggregate (x is [N,1]); layer2 aggregates only the 2-wide y = h1@W2.

static constexpr int BKT_BITS = 11;
static constexpr int BKT = 1 << BKT_BITS;  // 2048 nodes / dst-bucket
static constexpr int SRC_SH = 16;          // 64K-node src classes
static constexpr int NBIN_MAX = 2048;      // >= nbkt * C = 245*8 = 1960
static constexpr int CHUNK = 8192;         // edges per hist/scatter block
static constexpr int SCT = 256;
static constexpr int PERT = CHUNK / SCT;   // 32 edges/thread

using u32x4 = __attribute__((ext_vector_type(4))) unsigned;

// ---- 1. per-block bin histogram ----
__global__ void __launch_bounds__(SCT) k_hist(const int* __restrict__ src,
                                              const int* __restrict__ dst, int e,
                                              int nbin, int C,
                                              unsigned* __restrict__ hist) {
  __shared__ unsigned cnt[NBIN_MAX];
  for (int t = threadIdx.x; t < NBIN_MAX; t += SCT) cnt[t] = 0;
  __syncthreads();
  int lo = blockIdx.x * CHUNK;
  int hi = min(lo + CHUNK, e);
  const int4* s4 = (const int4*)src;
  const int4* d4 = (const int4*)dst;
  for (int i = (lo >> 2) + threadIdx.x; i < (hi >> 2); i += SCT) {
    int4 s = s4[i];
    int4 d = d4[i];
    atomicAdd(&cnt[(((unsigned)d.x) >> BKT_BITS) * C + (((unsigned)s.x) >> SRC_SH)], 1u);
    atomicAdd(&cnt[(((unsigned)d.y) >> BKT_BITS) * C + (((unsigned)s.y) >> SRC_SH)], 1u);
    atomicAdd(&cnt[(((unsigned)d.z) >> BKT_BITS) * C + (((unsigned)s.z) >> SRC_SH)], 1u);
    atomicAdd(&cnt[(((unsigned)d.w) >> BKT_BITS) * C + (((unsigned)s.w) >> SRC_SH)], 1u);
  }
  for (int i = ((hi >> 2) << 2) + threadIdx.x; i < hi; i += SCT)
    atomicAdd(&cnt[(((unsigned)dst[i]) >> BKT_BITS) * C + (((unsigned)src[i]) >> SRC_SH)], 1u);
  __syncthreads();
  unsigned* hrow = hist + (size_t)blockIdx.x * nbin;
  for (int t = threadIdx.x; t < nbin; t += SCT) hrow[t] = cnt[t];
}

// ---- 2. exclusive scan down each bin column (1 wave per bin) ----
__global__ void k_colscan(const unsigned* __restrict__ hist, int sgrid, int nbin,
                          unsigned* __restrict__ colpre,
                          unsigned* __restrict__ totals) {
  int k = blockIdx.x;
  int lane = threadIdx.x;  // 64
  unsigned running = 0;
  int rounds = (sgrid + 63) >> 6;
  for (int c = 0; c < rounds; ++c) {
    int b = c * 64 + lane;
    unsigned v = (b < sgrid) ? hist[(size_t)b * nbin + k] : 0u;
    unsigned incl = v;
#pragma unroll
    for (int off = 1; off < 64; off <<= 1) {
      unsigned t = __shfl_up(incl, off);
      if (lane >= off) incl += t;
    }
    if (b < sgrid) colpre[(size_t)b * nbin + k] = running + incl - v;
    running += __shfl(incl, 63);
  }
  if (lane == 0) totals[k] = running;
}

// ---- 3. exclusive scan of bin totals (single wave) ----
__global__ void k_binscan(const unsigned* __restrict__ totals, int nbin,
                          unsigned* __restrict__ base) {
  int lane = threadIdx.x;  // 64
  unsigned running = 0;
  for (int c = 0; c < NBIN_MAX; c += 64) {
    int k = c + lane;
    unsigned v = (k < nbin) ? totals[k] : 0u;
    unsigned incl = v;
#pragma unroll
    for (int off = 1; off < 64; off <<= 1) {
      unsigned t = __shfl_up(incl, off);
      if (lane >= off) incl += t;
    }
    if (k < nbin) base[k] = running + incl - v;
    running += __shfl(incl, 63);
  }
  if (lane == 0) base[nbin] = running;  // == e
}

// ---- 4. scatter: block-local bin sort + atomic-free linear copy-out ----
__global__ void __launch_bounds__(SCT) k_scatter(
    const int* __restrict__ src, const int* __restrict__ dst, int e, int nbin,
    int C, const unsigned* __restrict__ colpre, const unsigned* __restrict__ base,
    unsigned* __restrict__ packed) {
  __shared__ unsigned staged[CHUNK];       // 32 KB
  __shared__ unsigned cnt[NBIN_MAX];       // 8 KB (reused as cursor)
  __shared__ unsigned loff[NBIN_MAX + 1];  // 8 KB
  __shared__ unsigned gbase[NBIN_MAX];     // 8 KB
  const int tid = threadIdx.x;
  const int lo = blockIdx.x * CHUNK;
  for (int t = tid; t < NBIN_MAX; t += SCT) cnt[t] = 0u;
  __syncthreads();

  unsigned pk[PERT];
  unsigned short bin[PERT];
  const int4* s4 = (const int4*)src;
  const int4* d4 = (const int4*)dst;
#pragma unroll
  for (int jj = 0; jj < PERT / 4; ++jj) {
    int i4 = (lo >> 2) + jj * SCT + tid;
    if (i4 * 4 + 3 < e) {
      int4 s = s4[i4];
      int4 d = d4[i4];
      unsigned b0 = (((unsigned)d.x) >> BKT_BITS) * C + (((unsigned)s.x) >> SRC_SH);
      unsigned b1 = (((unsigned)d.y) >> BKT_BITS) * C + (((unsigned)s.y) >> SRC_SH);
      unsigned b2 = (((unsigned)d.z) >> BKT_BITS) * C + (((unsigned)s.z) >> SRC_SH);
      unsigned b3 = (((unsigned)d.w) >> BKT_BITS) * C + (((unsigned)s.w) >> SRC_SH);
      pk[jj * 4 + 0] = ((unsigned)s.x << BKT_BITS) | ((unsigned)d.x & (BKT - 1));
      pk[jj * 4 + 1] = ((unsigned)s.y << BKT_BITS) | ((unsigned)d.y & (BKT - 1));
      pk[jj * 4 + 2] = ((unsigned)s.z << BKT_BITS) | ((unsigned)d.z & (BKT - 1));
      pk[jj * 4 + 3] = ((unsigned)s.w << BKT_BITS) | ((unsigned)d.w & (BKT - 1));
      bin[jj * 4 + 0] = (unsigned short)b0;
      bin[jj * 4 + 1] = (unsigned short)b1;
      bin[jj * 4 + 2] = (unsigned short)b2;
      bin[jj * 4 + 3] = (unsigned short)b3;
      atomicAdd(&cnt[b0], 1u);
      atomicAdd(&cnt[b1], 1u);
      atomicAdd(&cnt[b2], 1u);
      atomicAdd(&cnt[b3], 1u);
    } else {
#pragma unroll
      for (int c = 0; c < 4; ++c) {
        int i = i4 * 4 + c;
        bin[jj * 4 + c] = 0xFFFFu;
        if (i >= lo && i < e) {
          unsigned ss = (unsigned)src[i];
          unsigned dd = (unsigned)dst[i];
          unsigned bb = (dd >> BKT_BITS) * C + (ss >> SRC_SH);
          pk[jj * 4 + c] = (ss << BKT_BITS) | (dd & (BKT - 1));
          bin[jj * 4 + c] = (unsigned short)bb;
          atomicAdd(&cnt[bb], 1u);
        }
      }
    }
  }
  __syncthreads();

  if (tid < 64) {  // wave-0 scan cnt -> loff
    unsigned running = 0;
    for (int c = 0; c < NBIN_MAX; c += 64) {
      int k = c + tid;
      unsigned v = cnt[k];
      unsigned incl = v;
#pragma unroll
      for (int off = 1; off < 64; off <<= 1) {
        unsigned t = __shfl_up(incl, off);
        if (tid >= off) incl += t;
      }
      loff[k] = running + incl - v;
      running += __shfl(incl, 63);
    }
    if (tid == 0) loff[NBIN_MAX] = running;
  }
  __syncthreads();
  // cursor reset + per-bin global dest base
  const unsigned* cp = colpre + (size_t)blockIdx.x * nbin;
  for (int t = tid; t < NBIN_MAX; t += SCT) {
    cnt[t] = 0u;
    if (t < nbin) gbase[t] = base[t] + cp[t];
  }
  __syncthreads();

#pragma unroll
  for (int jj = 0; jj < PERT; ++jj) {
    unsigned b = bin[jj];
    if (b != 0xFFFFu) {
      unsigned pos = loff[b] + atomicAdd(&cnt[b], 1u);
      staged[pos] = pk[jj];
    }
  }
  __syncthreads();

  int mv = (int)loff[NBIN_MAX];
  for (int t = tid; t < mv; t += SCT) {
    int a = 0, b = nbin;  // loff[a] <= t < loff[b]
    while (b - a > 1) {
      int mid = (a + b) >> 1;
      if ((int)loff[mid] <= t) a = mid; else b = mid;
    }
    __builtin_nontemporal_store(staged[t],
                                packed + gbase[a] + (unsigned)(t - (int)loff[a]));
  }
}

// ---- 5. per-bucket degree -> dinv, xs = dinv*x (u32x4 stream) ----
__global__ void __launch_bounds__(1024) k_degnode(
    const unsigned* __restrict__ packed, const unsigned* __restrict__ base, int C,
    const float* __restrict__ x, int n, float* __restrict__ dinv,
    float* __restrict__ xs) {
  __shared__ unsigned cnt[BKT];
  int k = blockIdx.x;
  for (int t = threadIdx.x; t < BKT; t += 1024) cnt[t] = 0;
  __syncthreads();
  unsigned lo = base[k * C], hi = base[(k + 1) * C];
  unsigned loA = (lo + 3u) & ~3u;
  unsigned hiA = hi & ~3u;
  if (loA > hi) loA = hi;
  if (hiA < loA) hiA = loA;
  for (unsigned i = lo + threadIdx.x; i < loA; i += 1024)
    atomicAdd(&cnt[packed[i] & (BKT - 1)], 1u);
  for (unsigned i = hiA + threadIdx.x; i < hi; i += 1024)
    atomicAdd(&cnt[packed[i] & (BKT - 1)], 1u);
  const u32x4* p4 = (const u32x4*)packed;
  for (unsigned q = (loA >> 2) + threadIdx.x; q < (hiA >> 2); q += 1024) {
    u32x4 p = __builtin_nontemporal_load(p4 + q);
    atomicAdd(&cnt[p.x & (BKT - 1)], 1u);
    atomicAdd(&cnt[p.y & (BKT - 1)], 1u);
    atomicAdd(&cnt[p.z & (BKT - 1)], 1u);
    atomicAdd(&cnt[p.w & (BKT - 1)], 1u);
  }
  __syncthreads();
  int g0 = k << BKT_BITS;
  for (int t = threadIdx.x; t < BKT; t += 1024) {
    int g = g0 + t;
    if (g < n) {
      float di = rsqrtf((float)(cnt[t] + 1u));  // +1 self-loop
      dinv[g] = di;
      xs[g] = di * x[g];
    }
  }
}

// ---- 6. layer-1 aggregate + fused MLP 1->32->2 -> yd ----
__global__ void __launch_bounds__(1024) k_accA2(
    const unsigned* __restrict__ packed, const unsigned* __restrict__ base, int C,
    const float* __restrict__ dinv, const float* __restrict__ xs,
    const float* __restrict__ W1, const float* __restrict__ b1,
    const float* __restrict__ W2, int n, float2* __restrict__ yd) {
  __shared__ float acc[BKT];
  __shared__ float sW1[32], sb1[32], sW2[64];
  if (threadIdx.x < 32) {
    sW1[threadIdx.x] = W1[threadIdx.x];
    sb1[threadIdx.x] = b1[threadIdx.x];
  } else if (threadIdx.x < 96) {
    sW2[threadIdx.x - 32] = W2[threadIdx.x - 32];
  }
  for (int t = threadIdx.x; t < BKT; t += 1024) acc[t] = 0.0f;
  __syncthreads();
  int k = blockIdx.x;
  unsigned lo = base[k * C], hi = base[(k + 1) * C];
  unsigned loA = (lo + 3u) & ~3u;
  unsigned hiA = hi & ~3u;
  if (loA > hi) loA = hi;
  if (hiA < loA) hiA = loA;
  for (unsigned i = lo + threadIdx.x; i < loA; i += 1024) {
    unsigned p = packed[i];
    atomicAdd(&acc[p & (BKT - 1)], xs[p >> BKT_BITS]);
  }
  for (unsigned i = hiA + threadIdx.x; i < hi; i += 1024) {
    unsigned p = packed[i];
    atomicAdd(&acc[p & (BKT - 1)], xs[p >> BKT_BITS]);
  }
  const u32x4* p4 = (const u32x4*)packed;
  for (unsigned q = (loA >> 2) + threadIdx.x; q < (hiA >> 2); q += 1024) {
    u32x4 p = __builtin_nontemporal_load(p4 + q);
    float v0 = xs[p.x >> BKT_BITS];
    float v1 = xs[p.y >> BKT_BITS];
    float v2 = xs[p.z >> BKT_BITS];
    float v3 = xs[p.w >> BKT_BITS];
    atomicAdd(&acc[p.x & (BKT - 1)], v0);
    atomicAdd(&acc[p.y & (BKT - 1)], v1);
    atomicAdd(&acc[p.z & (BKT - 1)], v2);
    atomicAdd(&acc[p.w & (BKT - 1)], v3);
  }
  __syncthreads();
  int g0 = k << BKT_BITS;
  for (int t = threadIdx.x; t < BKT; t += 1024) {
    int g = g0 + t;
    if (g >= n) continue;
    float di = dinv[g];
    float s = di * (acc[t] + xs[g]);  // self-loop: dinv^2*x = dinv*xs
    float y0 = 0.0f, y1 = 0.0f;
#pragma unroll
    for (int f = 0; f < 32; ++f) {
      float h = fmaxf(fmaf(s, sW1[f], sb1[f]), 0.0f);
      y0 = fmaf(h, sW2[2 * f + 0], y0);
      y1 = fmaf(h, sW2[2 * f + 1], y1);
    }
    yd[g] = make_float2(di * y0, di * y1);
  }
}

// ---- 7. layer-2 aggregate + fused log-softmax ----
__global__ void __launch_bounds__(1024) k_accB3(
    const unsigned* __restrict__ packed, const unsigned* __restrict__ base, int C,
    const float* __restrict__ dinv, const float2* __restrict__ yd,
    const float* __restrict__ b2, int n, float2* __restrict__ out) {
  __shared__ float a0[BKT], a1[BKT];
  for (int t = threadIdx.x; t < BKT; t += 1024) {
    a0[t] = 0.0f;
    a1[t] = 0.0f;
  }
  __syncthreads();
  int k = blockIdx.x;
  unsigned lo = base[k * C], hi = base[(k + 1) * C];
  unsigned loA = (lo + 3u) & ~3u;
  unsigned hiA = hi & ~3u;
  if (loA > hi) loA = hi;
  if (hiA < loA) hiA = loA;
  for (unsigned i = lo + threadIdx.x; i < loA; i += 1024) {
    unsigned p = packed[i];
    float2 v = yd[p >> BKT_BITS];
    atomicAdd(&a0[p & (BKT - 1)], v.x);
    atomicAdd(&a1[p & (BKT - 1)], v.y);
  }
  for (unsigned i = hiA + threadIdx.x; i < hi; i += 1024) {
    unsigned p = packed[i];
    float2 v = yd[p >> BKT_BITS];
    atomicAdd(&a0[p & (BKT - 1)], v.x);
    atomicAdd(&a1[p & (BKT - 1)], v.y);
  }
  const u32x4* p4 = (const u32x4*)packed;
  for (unsigned q = (loA >> 2) + threadIdx.x; q < (hiA >> 2); q += 1024) {
    u32x4 p = __builtin_nontemporal_load(p4 + q);
    float2 v0 = yd[p.x >> BKT_BITS];
    float2 v1 = yd[p.y >> BKT_BITS];
    float2 v2 = yd[p.z >> BKT_BITS];
    float2 v3 = yd[p.w >> BKT_BITS];
    atomicAdd(&a0[p.x & (BKT - 1)], v0.x);
    atomicAdd(&a1[p.x & (BKT - 1)], v0.y);
    atomicAdd(&a0[p.y & (BKT - 1)], v1.x);
    atomicAdd(&a1[p.y & (BKT - 1)], v1.y);
    atomicAdd(&a0[p.z & (BKT - 1)], v2.x);
    atomicAdd(&a1[p.z & (BKT - 1)], v2.y);
    atomicAdd(&a0[p.w & (BKT - 1)], v3.x);
    atomicAdd(&a1[p.w & (BKT - 1)], v3.y);
  }
  __syncthreads();
  float b20 = b2[0], b21 = b2[1];
  int g0 = k << BKT_BITS;
  for (int t = threadIdx.x; t < BKT; t += 1024) {
    int g = g0 + t;
    if (g >= n) continue;
    float di = dinv[g];
    float2 yv = yd[g];
    float t0 = fmaf(di, a0[t] + yv.x, b20);
    float t1 = fmaf(di, a1[t] + yv.y, b21);
    float m = fmaxf(t0, t1);
    float l = m + logf(expf(t0 - m) + expf(t1 - m));
    out[g] = make_float2(t0 - l, t1 - l);
  }
}

extern "C" void kernel_launch(void* const* d_in, const int* in_sizes, int n_in,
                              void* d_out, int out_size, void* d_ws, size_t ws_size,
                              hipStream_t stream) {
  const float* x = (const float*)d_in[0];
  const int* edge = (const int*)d_in[1];  // int64 inputs arrive as int32
  const float* W1 = (const float*)d_in[2];
  const float* b1 = (const float*)d_in[3];
  const float* W2 = (const float*)d_in[4];
  const float* b2 = (const float*)d_in[5];
  float2* out = (float2*)d_out;

  const int n = in_sizes[0];      // 500000
  const int e = in_sizes[1] / 2;  // 8000000
  const int* src = edge;
  const int* dst = edge + e;

  const int nbkt = (n + BKT - 1) >> BKT_BITS;  // 245
  const int C = (n + 65535) >> SRC_SH;         // 8 src classes
  const int nbin = nbkt * C;                   // 1960
  const int sgrid = (e + CHUNK - 1) / CHUNK;   // 977

  // ---- workspace (fixed ~55.5 MB; round-4 evidence ws >= 71 MB) ----
  char* ws = (char*)d_ws;
  size_t off = 0;
  unsigned* packed = (unsigned*)(ws + off); off += (size_t)e * 4;           // 32 MB
  unsigned* base = (unsigned*)(ws + off);   off += (NBIN_MAX + 2) * 4;
  unsigned* totals = (unsigned*)(ws + off); off += NBIN_MAX * 4;
  float* dinv = (float*)(ws + off);         off += (size_t)n * 4;           // 2 MB
  float* xs = (float*)(ws + off);           off += (size_t)n * 4;           // 2 MB
  float2* yd = (float2*)(ws + off);         off += (size_t)n * 8;           // 4 MB
  unsigned* hist = (unsigned*)(ws + off);   off += (size_t)sgrid * nbin * 4; // 7.7 MB
  unsigned* colpre = (unsigned*)(ws + off); off += (size_t)sgrid * nbin * 4; // 7.7 MB

  k_hist<<<sgrid, SCT, 0, stream>>>(src, dst, e, nbin, C, hist);
  k_colscan<<<nbin, 64, 0, stream>>>(hist, sgrid, nbin, colpre, totals);
  k_binscan<<<1, 64, 0, stream>>>(totals, nbin, base);
  k_scatter<<<sgrid, SCT, 0, stream>>>(src, dst, e, nbin, C, colpre, base, packed);
  k_degnode<<<nbkt, 1024, 0, stream>>>(packed, base, C, x, n, dinv, xs);
  k_accA2<<<nbkt, 1024, 0, stream>>>(packed, base, C, dinv, xs, W1, b1, W2, n, yd);
  k_accB3<<<nbkt, 1024, 0, stream>>>(packed, base, C, dinv, yd, b2, n, out);
}

// Round 7
// 253.927 us; speedup vs baseline: 1.2387x; 1.2387x over previous
//
#include <hip/hip_runtime.h>

// GCN1 on MI355X. Round-6 evidence: (dst_bucket, src_class) grouping fixed the
// consumers (all <~40us, TLB/locality theory confirmed) but the 1960-bin
// one-shot scatter regressed (127us, 89MB writes = 2.8x amp from 4-edge runs,
// 57KB LDS -> 19% occ). Round-7: two-level sort. Level 1 = proven round-3
// 245-bucket scatter (33-edge runs, ~33MB writes). Level 2 = per-bucket
// 8-class counting sort (k_classort) with per-(class,wave) cursors writing
// 128 exclusive sequential streams into the block's own segment (amp ~1).
// Degree counting is fused into classort phase 1 (kills the degnode pass).
//
// Algebra (validated r1-r6, absmax 3.9e-3): layer1 collapses to a scalar
// aggregate (x is [N,1]); layer2 aggregates only the 2-wide y = h1@W2.

static constexpr int BKT_BITS = 11;
static constexpr int BKT = 1 << BKT_BITS;  // 2048 nodes / dst-bucket
static constexpr int NB = 256;             // padded bucket count (nbkt=245)
static constexpr int HB = 512;             // hist blocks
static constexpr int HT = 256;
static constexpr int CHUNK = 8192;         // edges per scatter block
static constexpr int SCT = 256;
static constexpr int PERT = CHUNK / SCT;   // 32 edges/thread
static constexpr int CLS_SH = 27;          // class = packed>>27 == src>>16
static constexpr int NCLS = 8;             // 500000 >> 16 -> classes 0..7
static constexpr int NW = 16;              // waves per classort block (1024 thr)

using u32x4 = __attribute__((ext_vector_type(4))) unsigned;

// ---- 1. per-bucket totals: LDS histogram, one global add per bucket ----
__global__ void __launch_bounds__(HT) k_hist(const int* __restrict__ dst, int e,
                                             int chunk, int nbkt,
                                             unsigned* __restrict__ totals) {
  __shared__ unsigned cnt[NB];
  for (int t = threadIdx.x; t < NB; t += HT) cnt[t] = 0;
  __syncthreads();
  int lo = blockIdx.x * chunk;  // chunk multiple of 4
  int hi = min(lo + chunk, e);
  const int4* d4 = (const int4*)dst;
  for (int i = (lo >> 2) + threadIdx.x; i < (hi >> 2); i += HT) {
    int4 d = d4[i];
    atomicAdd(&cnt[((unsigned)d.x) >> BKT_BITS], 1u);
    atomicAdd(&cnt[((unsigned)d.y) >> BKT_BITS], 1u);
    atomicAdd(&cnt[((unsigned)d.z) >> BKT_BITS], 1u);
    atomicAdd(&cnt[((unsigned)d.w) >> BKT_BITS], 1u);
  }
  for (int i = ((hi >> 2) << 2) + threadIdx.x; i < hi; i += HT)
    atomicAdd(&cnt[((unsigned)dst[i]) >> BKT_BITS], 1u);
  __syncthreads();
  for (int t = threadIdx.x; t < nbkt; t += HT)
    if (cnt[t]) atomicAdd(&totals[t], cnt[t]);
}

// ---- 2. exclusive scan of totals -> gcur (single wave) ----
__global__ void k_basescan(const unsigned* __restrict__ totals, int nbkt,
                           unsigned* __restrict__ gcur) {
  int lane = threadIdx.x;  // blockDim = 64
  unsigned running = 0;
  for (int c = 0; c < NB; c += 64) {
    int k = c + lane;
    unsigned v = (k < nbkt) ? totals[k] : 0u;
    unsigned incl = v;
#pragma unroll
    for (int off = 1; off < 64; off <<= 1) {
      unsigned t = __shfl_up(incl, off);
      if (lane >= off) incl += t;
    }
    if (k < nbkt) gcur[k] = running + incl - v;
    running += __shfl(incl, 63);
  }
}

// ---- 3. scatter: block-local 245-bucket sort + linear copy-out ----
__global__ void __launch_bounds__(SCT) k_scatter(
    const int* __restrict__ src, const int* __restrict__ dst, int e, int nbkt,
    unsigned* __restrict__ gcur, unsigned* __restrict__ packed) {
  __shared__ unsigned staged[CHUNK];  // 32 KB
  __shared__ unsigned cnt[NB];
  __shared__ unsigned cur[NB];
  __shared__ unsigned gseg[NB];
  __shared__ unsigned loff[NB + 1];
  const int tid = threadIdx.x;
  const int lo = blockIdx.x * CHUNK;
  for (int t = tid; t < NB; t += SCT) { cnt[t] = 0u; cur[t] = 0u; }
  __syncthreads();

  unsigned pk[PERT];
  unsigned bku[PERT / 4];  // 4 bucket ids per u32 (0xFF = invalid)
  const int4* s4 = (const int4*)src;
  const int4* d4 = (const int4*)dst;
#pragma unroll
  for (int jj = 0; jj < PERT / 4; ++jj) {
    int i4 = (lo >> 2) + jj * SCT + tid;
    unsigned b4 = 0xFFFFFFFFu;
    if (i4 * 4 + 3 < e) {
      int4 s = s4[i4];
      int4 d = d4[i4];
      unsigned k0 = ((unsigned)d.x) >> BKT_BITS, k1 = ((unsigned)d.y) >> BKT_BITS;
      unsigned k2 = ((unsigned)d.z) >> BKT_BITS, k3 = ((unsigned)d.w) >> BKT_BITS;
      pk[jj * 4 + 0] = ((unsigned)s.x << BKT_BITS) | ((unsigned)d.x & (BKT - 1));
      pk[jj * 4 + 1] = ((unsigned)s.y << BKT_BITS) | ((unsigned)d.y & (BKT - 1));
      pk[jj * 4 + 2] = ((unsigned)s.z << BKT_BITS) | ((unsigned)d.z & (BKT - 1));
      pk[jj * 4 + 3] = ((unsigned)s.w << BKT_BITS) | ((unsigned)d.w & (BKT - 1));
      b4 = k0 | (k1 << 8) | (k2 << 16) | (k3 << 24);
      atomicAdd(&cnt[k0], 1u);
      atomicAdd(&cnt[k1], 1u);
      atomicAdd(&cnt[k2], 1u);
      atomicAdd(&cnt[k3], 1u);
    } else {
#pragma unroll
      for (int c = 0; c < 4; ++c) {
        int i = i4 * 4 + c;
        if (i >= lo && i < e) {
          unsigned dd = (unsigned)dst[i];
          unsigned kk = dd >> BKT_BITS;
          pk[jj * 4 + c] = ((unsigned)src[i] << BKT_BITS) | (dd & (BKT - 1));
          b4 = (b4 & ~(0xFFu << (8 * c))) | (kk << (8 * c));
          atomicAdd(&cnt[kk], 1u);
        }
      }
    }
    bku[jj] = b4;
  }
  __syncthreads();

  if (tid < 64) {  // wave-0 scan cnt -> loff
    unsigned running = 0;
    for (int c = 0; c < NB; c += 64) {
      int k = c + tid;
      unsigned v = cnt[k];
      unsigned incl = v;
#pragma unroll
      for (int off = 1; off < 64; off <<= 1) {
        unsigned t = __shfl_up(incl, off);
        if (tid >= off) incl += t;
      }
      loff[k] = running + incl - v;
      running += __shfl(incl, 63);
    }
    if (tid == 0) loff[NB] = running;
  }
  __syncthreads();

  for (int k = tid; k < nbkt; k += SCT)
    if (cnt[k]) gseg[k] = atomicAdd(&gcur[k], cnt[k]);

#pragma unroll
  for (int jj = 0; jj < PERT / 4; ++jj) {
    unsigned b4 = bku[jj];
#pragma unroll
    for (int c = 0; c < 4; ++c) {
      unsigned k = (b4 >> (8 * c)) & 0xFFu;
      if (k != 0xFFu) {
        unsigned pos = loff[k] + atomicAdd(&cur[k], 1u);
        staged[pos] = pk[jj * 4 + c];
      }
    }
  }
  __syncthreads();

  int mv = (int)loff[NB];
  for (int t = tid; t < mv; t += SCT) {
    int a = 0, b = nbkt;  // loff[a] <= t < loff[b]
    while (b - a > 1) {
      int mid = (a + b) >> 1;
      if ((int)loff[mid] <= t) a = mid; else b = mid;
    }
    __builtin_nontemporal_store(staged[t],
                                packed + gseg[a] + (unsigned)(t - (int)loff[a]));
  }
}

// ---- 4. per-bucket class sort (src>>16) + fused degree -> dinv, xs ----
__global__ void __launch_bounds__(1024) k_classort(
    const unsigned* __restrict__ packed, const unsigned* __restrict__ gcur,
    const float* __restrict__ x, int n, unsigned* __restrict__ packed2,
    float* __restrict__ dinv, float* __restrict__ xs) {
  __shared__ unsigned cnt_node[BKT];       // 8 KB
  __shared__ unsigned wcnt[NCLS * NW];     // [class][wave] counts
  __shared__ unsigned wcur[NCLS * NW];     // live cursors (bases after scan)
  const int k = blockIdx.x;
  const int tid = threadIdx.x;
  const int w = tid >> 6;
  for (int t = tid; t < BKT; t += 1024) cnt_node[t] = 0;
  if (tid < NCLS * NW) wcnt[tid] = 0;
  __syncthreads();
  unsigned lo = k ? gcur[k - 1] : 0u, hi = gcur[k];
  unsigned loA = (lo + 3u) & ~3u, hiA = hi & ~3u;
  if (loA > hi) loA = hi;
  if (hiA < loA) hiA = loA;

  // phase 1: node degree + per-(class,wave) counts
  for (unsigned i = lo + tid; i < loA; i += 1024) {
    unsigned p = packed[i];
    atomicAdd(&cnt_node[p & (BKT - 1)], 1u);
    atomicAdd(&wcnt[(p >> CLS_SH) * NW + w], 1u);
  }
  for (unsigned i = hiA + tid; i < hi; i += 1024) {
    unsigned p = packed[i];
    atomicAdd(&cnt_node[p & (BKT - 1)], 1u);
    atomicAdd(&wcnt[(p >> CLS_SH) * NW + w], 1u);
  }
  const u32x4* p4 = (const u32x4*)packed;
  for (unsigned q = (loA >> 2) + tid; q < (hiA >> 2); q += 1024) {
    u32x4 p = p4[q];  // stays L2-hot for phase 2
    atomicAdd(&cnt_node[p.x & (BKT - 1)], 1u);
    atomicAdd(&wcnt[(p.x >> CLS_SH) * NW + w], 1u);
    atomicAdd(&cnt_node[p.y & (BKT - 1)], 1u);
    atomicAdd(&wcnt[(p.y >> CLS_SH) * NW + w], 1u);
    atomicAdd(&cnt_node[p.z & (BKT - 1)], 1u);
    atomicAdd(&wcnt[(p.z >> CLS_SH) * NW + w], 1u);
    atomicAdd(&cnt_node[p.w & (BKT - 1)], 1u);
    atomicAdd(&wcnt[(p.w >> CLS_SH) * NW + w], 1u);
  }
  __syncthreads();

  // wave-0 exclusive scan of the 128 (class-major, wave-minor) counts
  if (tid < 64) {
    unsigned running = 0;
#pragma unroll
    for (int r = 0; r < (NCLS * NW) / 64; ++r) {
      int idx = r * 64 + tid;
      unsigned v = wcnt[idx];
      unsigned incl = v;
#pragma unroll
      for (int off = 1; off < 64; off <<= 1) {
        unsigned t = __shfl_up(incl, off);
        if (tid >= off) incl += t;
      }
      wcur[idx] = running + incl - v;
      running += __shfl(incl, 63);
    }
  }
  __syncthreads();

  // phase 2: place into class-grouped order (128 exclusive seq streams)
  for (unsigned i = lo + tid; i < loA; i += 1024) {
    unsigned p = packed[i];
    unsigned pos = atomicAdd(&wcur[(p >> CLS_SH) * NW + w], 1u);
    packed2[lo + pos] = p;
  }
  for (unsigned i = hiA + tid; i < hi; i += 1024) {
    unsigned p = packed[i];
    unsigned pos = atomicAdd(&wcur[(p >> CLS_SH) * NW + w], 1u);
    packed2[lo + pos] = p;
  }
  for (unsigned q = (loA >> 2) + tid; q < (hiA >> 2); q += 1024) {
    u32x4 p = p4[q];
    unsigned pos0 = atomicAdd(&wcur[(p.x >> CLS_SH) * NW + w], 1u);
    packed2[lo + pos0] = p.x;
    unsigned pos1 = atomicAdd(&wcur[(p.y >> CLS_SH) * NW + w], 1u);
    packed2[lo + pos1] = p.y;
    unsigned pos2 = atomicAdd(&wcur[(p.z >> CLS_SH) * NW + w], 1u);
    packed2[lo + pos2] = p.z;
    unsigned pos3 = atomicAdd(&wcur[(p.w >> CLS_SH) * NW + w], 1u);
    packed2[lo + pos3] = p.w;
  }

  // epilogue (cnt_node final since first post-phase-1 barrier)
  int g0 = k << BKT_BITS;
  for (int t = tid; t < BKT; t += 1024) {
    int g = g0 + t;
    if (g < n) {
      float di = rsqrtf((float)(cnt_node[t] + 1u));  // +1 self-loop
      dinv[g] = di;
      xs[g] = di * x[g];
    }
  }
}

// ---- 5. layer-1 aggregate + fused MLP 1->32->2 -> yd ----
__global__ void __launch_bounds__(1024) k_accA2(
    const unsigned* __restrict__ packed2, const unsigned* __restrict__ gcur,
    const float* __restrict__ dinv, const float* __restrict__ xs,
    const float* __restrict__ W1, const float* __restrict__ b1,
    const float* __restrict__ W2, int n, float2* __restrict__ yd) {
  __shared__ float acc[BKT];
  __shared__ float sW1[32], sb1[32], sW2[64];
  if (threadIdx.x < 32) {
    sW1[threadIdx.x] = W1[threadIdx.x];
    sb1[threadIdx.x] = b1[threadIdx.x];
  } else if (threadIdx.x < 96) {
    sW2[threadIdx.x - 32] = W2[threadIdx.x - 32];
  }
  for (int t = threadIdx.x; t < BKT; t += 1024) acc[t] = 0.0f;
  __syncthreads();
  int k = blockIdx.x;
  unsigned lo = k ? gcur[k - 1] : 0u, hi = gcur[k];
  unsigned loA = (lo + 3u) & ~3u, hiA = hi & ~3u;
  if (loA > hi) loA = hi;
  if (hiA < loA) hiA = loA;
  for (unsigned i = lo + threadIdx.x; i < loA; i += 1024) {
    unsigned p = packed2[i];
    atomicAdd(&acc[p & (BKT - 1)], xs[p >> BKT_BITS]);
  }
  for (unsigned i = hiA + threadIdx.x; i < hi; i += 1024) {
    unsigned p = packed2[i];
    atomicAdd(&acc[p & (BKT - 1)], xs[p >> BKT_BITS]);
  }
  const u32x4* p4 = (const u32x4*)packed2;
  for (unsigned q = (loA >> 2) + threadIdx.x; q < (hiA >> 2); q += 1024) {
    u32x4 p = __builtin_nontemporal_load(p4 + q);
    float v0 = xs[p.x >> BKT_BITS];
    float v1 = xs[p.y >> BKT_BITS];
    float v2 = xs[p.z >> BKT_BITS];
    float v3 = xs[p.w >> BKT_BITS];
    atomicAdd(&acc[p.x & (BKT - 1)], v0);
    atomicAdd(&acc[p.y & (BKT - 1)], v1);
    atomicAdd(&acc[p.z & (BKT - 1)], v2);
    atomicAdd(&acc[p.w & (BKT - 1)], v3);
  }
  __syncthreads();
  int g0 = k << BKT_BITS;
  for (int t = threadIdx.x; t < BKT; t += 1024) {
    int g = g0 + t;
    if (g >= n) continue;
    float di = dinv[g];
    float s = di * (acc[t] + xs[g]);  // self-loop: dinv^2*x = dinv*xs
    float y0 = 0.0f, y1 = 0.0f;
#pragma unroll
    for (int f = 0; f < 32; ++f) {
      float h = fmaxf(fmaf(s, sW1[f], sb1[f]), 0.0f);
      y0 = fmaf(h, sW2[2 * f + 0], y0);
      y1 = fmaf(h, sW2[2 * f + 1], y1);
    }
    yd[g] = make_float2(di * y0, di * y1);
  }
}

// ---- 6. layer-2 aggregate + fused log-softmax ----
__global__ void __launch_bounds__(1024) k_accB3(
    const unsigned* __restrict__ packed2, const unsigned* __restrict__ gcur,
    const float* __restrict__ dinv, const float2* __restrict__ yd,
    const float* __restrict__ b2, int n, float2* __restrict__ out) {
  __shared__ float a0[BKT], a1[BKT];
  for (int t = threadIdx.x; t < BKT; t += 1024) {
    a0[t] = 0.0f;
    a1[t] = 0.0f;
  }
  __syncthreads();
  int k = blockIdx.x;
  unsigned lo = k ? gcur[k - 1] : 0u, hi = gcur[k];
  unsigned loA = (lo + 3u) & ~3u, hiA = hi & ~3u;
  if (loA > hi) loA = hi;
  if (hiA < loA) hiA = loA;
  for (unsigned i = lo + threadIdx.x; i < loA; i += 1024) {
    unsigned p = packed2[i];
    float2 v = yd[p >> BKT_BITS];
    atomicAdd(&a0[p & (BKT - 1)], v.x);
    atomicAdd(&a1[p & (BKT - 1)], v.y);
  }
  for (unsigned i = hiA + threadIdx.x; i < hi; i += 1024) {
    unsigned p = packed2[i];
    float2 v = yd[p >> BKT_BITS];
    atomicAdd(&a0[p & (BKT - 1)], v.x);
    atomicAdd(&a1[p & (BKT - 1)], v.y);
  }
  const u32x4* p4 = (const u32x4*)packed2;
  for (unsigned q = (loA >> 2) + threadIdx.x; q < (hiA >> 2); q += 1024) {
    u32x4 p = __builtin_nontemporal_load(p4 + q);
    float2 v0 = yd[p.x >> BKT_BITS];
    float2 v1 = yd[p.y >> BKT_BITS];
    float2 v2 = yd[p.z >> BKT_BITS];
    float2 v3 = yd[p.w >> BKT_BITS];
    atomicAdd(&a0[p.x & (BKT - 1)], v0.x);
    atomicAdd(&a1[p.x & (BKT - 1)], v0.y);
    atomicAdd(&a0[p.y & (BKT - 1)], v1.x);
    atomicAdd(&a1[p.y & (BKT - 1)], v1.y);
    atomicAdd(&a0[p.z & (BKT - 1)], v2.x);
    atomicAdd(&a1[p.z & (BKT - 1)], v2.y);
    atomicAdd(&a0[p.w & (BKT - 1)], v3.x);
    atomicAdd(&a1[p.w & (BKT - 1)], v3.y);
  }
  __syncthreads();
  float b20 = b2[0], b21 = b2[1];
  int g0 = k << BKT_BITS;
  for (int t = threadIdx.x; t < BKT; t += 1024) {
    int g = g0 + t;
    if (g >= n) continue;
    float di = dinv[g];
    float2 yv = yd[g];
    float t0 = fmaf(di, a0[t] + yv.x, b20);
    float t1 = fmaf(di, a1[t] + yv.y, b21);
    float m = fmaxf(t0, t1);
    float l = m + logf(expf(t0 - m) + expf(t1 - m));
    out[g] = make_float2(t0 - l, t1 - l);
  }
}

extern "C" void kernel_launch(void* const* d_in, const int* in_sizes, int n_in,
                              void* d_out, int out_size, void* d_ws, size_t ws_size,
                              hipStream_t stream) {
  const float* x = (const float*)d_in[0];
  const int* edge = (const int*)d_in[1];  // int64 inputs arrive as int32
  const float* W1 = (const float*)d_in[2];
  const float* b1 = (const float*)d_in[3];
  const float* W2 = (const float*)d_in[4];
  const float* b2 = (const float*)d_in[5];
  float2* out = (float2*)d_out;

  const int n = in_sizes[0];      // 500000
  const int e = in_sizes[1] / 2;  // 8000000
  const int* src = edge;
  const int* dst = edge + e;

  const int nbkt = (n + BKT - 1) >> BKT_BITS;         // 245
  const int hchunk = (((e + HB - 1) / HB) + 3) & ~3;  // mult of 4
  const int sgrid = (e + CHUNK - 1) / CHUNK;          // 977

  // ---- workspace (~72.0 MB; round-4 demonstrated ws >= 72.1 MB) ----
  char* ws = (char*)d_ws;
  size_t off = 0;
  unsigned* packed = (unsigned*)(ws + off);  off += (size_t)e * 4;   // 32 MB
  unsigned* packed2 = (unsigned*)(ws + off); off += (size_t)e * 4;   // 32 MB
  unsigned* totals = (unsigned*)(ws + off);  off += NB * 4;
  unsigned* gcur = (unsigned*)(ws + off);    off += NB * 4;
  float* dinv = (float*)(ws + off);          off += (size_t)n * 4;   // 2 MB
  float* xs = (float*)(ws + off);            off += (size_t)n * 4;   // 2 MB
  float2* yd = (float2*)(ws + off);          off += (size_t)n * 8;   // 4 MB

  hipMemsetAsync(totals, 0, NB * sizeof(unsigned), stream);
  k_hist<<<HB, HT, 0, stream>>>(dst, e, hchunk, nbkt, totals);
  k_basescan<<<1, 64, 0, stream>>>(totals, nbkt, gcur);
  k_scatter<<<sgrid, SCT, 0, stream>>>(src, dst, e, nbkt, gcur, packed);
  // after k_scatter: gcur[k] == end of bucket k
  k_classort<<<nbkt, 1024, 0, stream>>>(packed, gcur, x, n, packed2, dinv, xs);
  k_accA2<<<nbkt, 1024, 0, stream>>>(packed2, gcur, dinv, xs, W1, b1, W2, n, yd);
  k_accB3<<<nbkt, 1024, 0, stream>>>(packed2, gcur, dinv, yd, b2, n, out);
}